// Round 11
// baseline (425.075 us; speedup 1.0000x reference)
//
#include <hip/hip_runtime.h>

#define DD 64
#define RB 256         // rows per bucket
#define RB_SHIFT 8
#define CAP 4608       // LDS-sorted edge capacity per bucket (avg 4096, +8 sigma)
#define NBLKA 512      // blocks in the two bucketing passes (pow2; must match)
#define NBLKA_SHIFT 9
#define BMAX 1024      // max buckets (n <= BMAX*RB, col fits 18 bits)
#define COLM 0x3FFFF
#define WT_STRIDE 80   // padded k-stride of transposed bf16 W in LDS (16B-aligned rows)
#define EMAX 2368      // R21: halved (was 4704) -> LDS 74->46KB, 3 blocks/CU (was 2);
                       // exactly 2 sub-chunks per 4688-edge block chunk
#define SPAD 68        // padded fp32 stride of the LDS side tile (2-way max on frag reads)

typedef __attribute__((ext_vector_type(8))) short bf16x8;
typedef __attribute__((ext_vector_type(4))) float f32x4;

static __device__ __forceinline__ float leaky(float x) {
    return x > 0.f ? x : 0.2f * x;
}

// fp32 -> bf16 bits, round-to-nearest-even
static __device__ __forceinline__ unsigned short f2bf(float f) {
    unsigned u = __float_as_uint(f);
    unsigned r = 0x7FFFu + ((u >> 16) & 1u);
    return (unsigned short)((u + r) >> 16);
}
#define BF_LO(w) __int_as_float((int)((w) << 16))
#define BF_HI(w) __int_as_float((int)((w) & 0xFFFF0000u))

static __device__ __forceinline__ bf16x8 pack8(float a, float b, float c, float d,
                                               float e, float f, float g, float h) {
    bf16x8 r;
    r[0] = (short)f2bf(a); r[1] = (short)f2bf(b); r[2] = (short)f2bf(c); r[3] = (short)f2bf(d);
    r[4] = (short)f2bf(e); r[5] = (short)f2bf(f); r[6] = (short)f2bf(g); r[7] = (short)f2bf(h);
    return r;
}

// R19: concat + one-time W transpose merged (blockIdx branch).
// wtrans branch: W (fp32 [k][c]) -> Wt (bf16 [c][k]) via padded LDS tile —
// both global sides coalesced (R15 post-mortem).
__global__ void concat_wtrans_kernel(const float4* __restrict__ ue,
                                     const float4* __restrict__ ie,
                                     float4* __restrict__ ego, ushort4* __restrict__ egob,
                                     int n_user4, int total4, int cblocks,
                                     const float* __restrict__ Wg, const float* __restrict__ Wb,
                                     ushort* __restrict__ wtg, ushort* __restrict__ wtb, int L) {
    __shared__ ushort t[64][65];
    int tid = threadIdx.x;
    if ((int)blockIdx.x >= cblocks) {
        int which = blockIdx.x - cblocks;  // 0..2L-1
        const float* src = (which < L) ? Wg + (size_t)which * 4096
                                       : Wb + (size_t)(which - L) * 4096;
        ushort* dst = (which < L) ? wtg + (size_t)which * 4096
                                  : wtb + (size_t)(which - L) * 4096;
        for (int i = tid; i < 4096; i += 256) {
            int k = i >> 6, c = i & 63;
            t[k][c] = f2bf(src[i]);      // coalesced read; 2B-stride LDS write
        }
        __syncthreads();
        for (int i = tid; i < 4096; i += 256) {
            int c = i >> 6, k = i & 63;
            dst[i] = t[k][c];            // coalesced write; ~2-way LDS read (65-pad)
        }
        return;
    }
    int idx = blockIdx.x * 256 + tid;
    if (idx >= total4) return;
    float4 v = (idx < n_user4) ? ue[idx] : ie[idx - n_user4];
    ego[idx] = v;
    ushort4 b;
    b.x = f2bf(v.x); b.y = f2bf(v.y); b.z = f2bf(v.z); b.w = f2bf(v.w);
    egob[idx] = b;
}

// pass A: per-(bucket, block) histogram via LDS — no global atomics.
// Flat per-(bucket,block) offsets (R19 post-mortem: global atomic cursors
// serialized bscatter — 512 blocks blocking on same-address atomic returns).
__global__ void bhist_kernel(const int* __restrict__ rows, int* __restrict__ counts_t, int nnz,
                             int nbuckets) {
    __shared__ int h[BMAX];
    int tid = threadIdx.x, blk = blockIdx.x;
    for (int i = tid; i < nbuckets; i += 256) h[i] = 0;
    __syncthreads();
    int chunk = (nnz + NBLKA - 1) / NBLKA;
    int lo = blk * chunk, hi = min(nnz, lo + chunk);
    for (int e = lo + tid; e < hi; e += 256) atomicAdd(&h[rows[e] >> RB_SHIFT], 1);
    __syncthreads();
    for (int i = tid; i < nbuckets; i += 256) counts_t[blk * nbuckets + i] = h[i];
}

// scan over flat order f = bucket*NBLKA + blk, reading transposed counts.
__global__ void scan1_kernel(const int* __restrict__ counts_t, int* __restrict__ offsets,
                             int* __restrict__ blocksums, int flat, int nbuckets) {
    __shared__ int tmp[1024];
    int t = threadIdx.x;
    int g = blockIdx.x * 1024 + t;
    int x = 0;
    if (g < flat) {
        int i = g >> NBLKA_SHIFT, blk = g & (NBLKA - 1);
        x = counts_t[blk * nbuckets + i];
    }
    tmp[t] = x;
    __syncthreads();
    for (int off = 1; off < 1024; off <<= 1) {
        int y = (t >= off) ? tmp[t - off] : 0;
        __syncthreads();
        tmp[t] += y;
        __syncthreads();
    }
    if (g < flat) offsets[g + 1] = tmp[t];
    if (t == 1023) blocksums[blockIdx.x] = tmp[t];
    if (g == 0) offsets[0] = 0;
}

__global__ void scan2_kernel(int* blocksums, int nb) {
    __shared__ int tmp[1024];
    int t = threadIdx.x;
    int v = (t < nb) ? blocksums[t] : 0;
    tmp[t] = v;
    __syncthreads();
    for (int off = 1; off < 1024; off <<= 1) {
        int y = (t >= off) ? tmp[t - off] : 0;
        __syncthreads();
        tmp[t] += y;
        __syncthreads();
    }
    if (t < nb) blocksums[t] = tmp[t] - v;  // exclusive base per block
}

__global__ void scan3_kernel(int* __restrict__ offsets, const int* __restrict__ blocksums,
                             int n) {
    int g = blockIdx.x * 1024 + threadIdx.x;
    if (g < n) offsets[g + 1] += blocksums[blockIdx.x];
}

// pass B: LDS bucket-sort the block's chunk, then write back with consecutive
// lanes -> consecutive global addresses (coalesced path is load-bearing —
// R14: direct random 8B scatter = 8x write amplification). Write bases come
// from the precomputed contention-free offset table.
__global__ void __launch_bounds__(256) bscatter_kernel(
    const int* __restrict__ rows, const int* __restrict__ cols,
    const float* __restrict__ vals, const int* __restrict__ offsets,
    int2* __restrict__ csr_cv, int nnz, int nbuckets) {
    __shared__ int hist[BMAX];
    __shared__ int lbase[BMAX];
    __shared__ int cur[BMAX];
    __shared__ int gcur[BMAX];
    __shared__ int tsum[256];
    __shared__ int2 buf[EMAX];
    __shared__ int dst[EMAX];
    int tid = threadIdx.x, blk = blockIdx.x;
    int chunk = (nnz + NBLKA - 1) / NBLKA;
    int lo = blk * chunk, hi = min(nnz, lo + chunk);
    for (int i = tid; i < BMAX; i += 256)
        gcur[i] = (i < nbuckets) ? offsets[i * NBLKA + blk] : 0;
    for (int sub = lo; sub < hi; sub += EMAX) {
        int scount = min(EMAX, hi - sub);
        for (int i = tid; i < BMAX; i += 256) hist[i] = 0;
        __syncthreads();
        for (int e = sub + tid; e < sub + scount; e += 256)
            atomicAdd(&hist[rows[e] >> RB_SHIFT], 1);
        __syncthreads();
        int loc[4];
        int s = 0;
        int bi = tid * 4;
#pragma unroll
        for (int j = 0; j < 4; ++j) { loc[j] = s; s += hist[bi + j]; }
        tsum[tid] = s;
        __syncthreads();
        for (int off = 1; off < 256; off <<= 1) {
            int v = (tid >= off) ? tsum[tid - off] : 0;
            __syncthreads();
            tsum[tid] += v;
            __syncthreads();
        }
        int excl = tid ? tsum[tid - 1] : 0;
#pragma unroll
        for (int j = 0; j < 4; ++j) {
            lbase[bi + j] = excl + loc[j];
            cur[bi + j] = excl + loc[j];
        }
        __syncthreads();
        for (int e = sub + tid; e < sub + scount; e += 256) {
            int r = rows[e];
            int b = r >> RB_SHIFT;
            int p = atomicAdd(&cur[b], 1);
            int2 cv;
            cv.x = ((r & (RB - 1)) << 18) | cols[e];  // row_low(8b) | col(18b)
            cv.y = __float_as_int(vals[e]);
            buf[p] = cv;
            dst[p] = gcur[b] + (p - lbase[b]);
        }
        __syncthreads();
        for (int k = tid; k < scount; k += 256) csr_cv[dst[k]] = buf[k];
        __syncthreads();
        for (int i = tid; i < BMAX; i += 256) gcur[i] += hist[i];
        __syncthreads();
    }
}

// ONE-TIME sort: per bucket, counting-sort edges by row; LDS fast path, direct
// global scatter fallback for oversized buckets.
__global__ void __launch_bounds__(256) sort_kernel(
    const int* __restrict__ offsets, const int2* __restrict__ csr_cv,
    int2* __restrict__ sorted_cv, int* __restrict__ rowoff_g, int nnz, int nbuckets) {
    __shared__ int2 sorted[CAP];
    __shared__ int hist[RB];
    __shared__ int rowoff[RB + 1];
    __shared__ int cur[RB];
    int tid = threadIdx.x;
    int b = blockIdx.x;
    int s = offsets[b * NBLKA];
    int e = offsets[(b + 1) * NBLKA];
    int m = e - s;

    hist[tid] = 0;
    __syncthreads();
    for (int k = s + tid; k < e; k += 256)
        atomicAdd(&hist[((unsigned)csr_cv[k].x) >> 18], 1);
    __syncthreads();
    for (int off = 1; off < RB; off <<= 1) {
        int v = (tid >= off) ? hist[tid - off] : 0;
        __syncthreads();
        hist[tid] += v;
        __syncthreads();
    }
    rowoff[tid + 1] = hist[tid];
    if (tid == 0) rowoff[0] = 0;
    __syncthreads();
    cur[tid] = rowoff[tid];
    __syncthreads();
    if (m <= CAP) {
        for (int k = s + tid; k < e; k += 256) {
            int2 cv = csr_cv[k];
            int p = atomicAdd(&cur[((unsigned)cv.x) >> 18], 1);
            sorted[p] = cv;
        }
        __syncthreads();
        for (int k = tid; k < m; k += 256) sorted_cv[s + k] = sorted[k];
    } else {
        // rare fallback: scatter straight to global (uncoalesced, correct)
        for (int k = s + tid; k < e; k += 256) {
            int2 cv = csr_cv[k];
            int p = atomicAdd(&cur[((unsigned)cv.x) >> 18], 1);
            sorted_cv[s + p] = cv;
        }
    }
    rowoff_g[b * RB + tid] = s + rowoff[tid];
    if (b == 0 && tid == 0) rowoff_g[nbuckets * RB] = nnz;
}

// per-edge accumulate: acc[0..7] += v * unpack(g)
#define EDGE8(acc, cvy, g)                                                     \
    do {                                                                       \
        float v_ = __int_as_float(cvy);                                        \
        acc[0] += v_ * BF_LO((g).x); acc[1] += v_ * BF_HI((g).x);              \
        acc[2] += v_ * BF_LO((g).y); acc[3] += v_ * BF_HI((g).y);              \
        acc[4] += v_ * BF_LO((g).z); acc[5] += v_ * BF_HI((g).z);              \
        acc[6] += v_ * BF_LO((g).w); acc[7] += v_ * BF_HI((g).w);              \
    } while (0)

// FUSED layer: spmm (side into LDS) + MFMA transform, per 64-row block,
// 512 threads / 8 waves (32 waves/CU; phase 1 at the random-gather fabric
// wall — rate pinned ~3.45 TB/s, so traffic cuts convert to time).
// R21: phase-2 bi-interaction input e read from egob (bf16, 19.2 MB/layer)
// instead of ego (fp32, 38.4 MB/layer) — the product e*s is bf16-rounded by
// pack8 anyway, so pre-rounded e adds <=2^-9 relative on the bi branch only.
// Trailing blocks perform the PREVIOUS layer's output gather (R19).
__global__ void __launch_bounds__(512, 8) fused_layer_kernel(
    const uint4* __restrict__ egob_old, const float* __restrict__ ego_old,
    float* __restrict__ ego_new, ushort* __restrict__ egob_new,
    const int* __restrict__ rowoff, const int2* __restrict__ sorted_cv,
    const ushort* __restrict__ Wtg, const float* __restrict__ bgc,
    const ushort* __restrict__ Wtb, const float* __restrict__ bbi, int n,
    int fblocks, const int* __restrict__ u, const int* __restrict__ ii,
    const int* __restrict__ jj, float* __restrict__ out, int B, int n_users,
    int glayer, int gnorm, int ostride) {
    __shared__ __align__(16) float sideL[64 * SPAD];
    __shared__ __align__(16) ushort sWg[DD * WT_STRIDE];
    __shared__ __align__(16) ushort sWb[DD * WT_STRIDE];
    int tid = threadIdx.x;
    int wave = tid >> 6, lane = tid & 63;

    if ((int)blockIdx.x >= fblocks) {
        // gather branch: one wave per (arr, b) id; reads ego_old (prev output)
        int wid = (blockIdx.x - fblocks) * 8 + wave;
        if (wid < 3 * B) {
            int arr = wid / B;
            int b = wid - arr * B;
            int node = (arr == 0) ? u[b] : ((arr == 1) ? n_users + ii[b] : n_users + jj[b]);
            float v = ego_old[(size_t)node * DD + lane];
            if (gnorm) {
                float ss = v * v;
#pragma unroll
                for (int m = 32; m; m >>= 1) ss += __shfl_xor(ss, m, 64);
                v /= fmaxf(sqrtf(ss), 1e-12f);
            }
            out[(size_t)wid * ostride + glayer * DD + lane] = v;
        }
        return;
    }

    // staging: Wt is [c][k] bf16; coalesced global read, conflict-free LDS write
    for (int idx = tid; idx < DD * DD / 4; idx += 512) {
        int c = idx >> 4, k4 = idx & 15;
        *(ushort4*)&sWg[c * WT_STRIDE + k4 * 4] = ((const ushort4*)Wtg)[idx];
        *(ushort4*)&sWb[c * WT_STRIDE + k4 * 4] = ((const ushort4*)Wtb)[idx];
    }
    int base64 = blockIdx.x * 64;
    int sub = lane >> 3, l8 = lane & 7;

    // phase 1: single-stream spmm, 8 waves x 8 rows
    int lr0 = wave * 8 + sub;
    int row0 = base64 + lr0;
    float acc0[8] = {0.f, 0.f, 0.f, 0.f, 0.f, 0.f, 0.f, 0.f};
    int k0 = 0, E0 = 0;
    if (row0 < n) { k0 = rowoff[row0]; E0 = rowoff[row0 + 1]; }
    int CL0 = (E0 > 0) ? E0 - 1 : 0;   // clamped (valid, cache-hot) edge index

    // wave-uniform trip count: max over the 8 lane-groups (lane bits 3..5)
    int myit = (E0 - k0 + 3) >> 2;
    myit = max(myit, __shfl_xor(myit, 8, 64));
    myit = max(myit, __shfl_xor(myit, 16, 64));
    myit = max(myit, __shfl_xor(myit, 32, 64));

    int2 cA0[4];
#pragma unroll
    for (int j = 0; j < 4; ++j) {
        int i0 = k0 + j; cA0[j] = sorted_cv[i0 < E0 ? i0 : CL0];
    }
    for (int it = 0; it < myit; ++it) {
        // issue the 4 gathers (straight-line: compiler pipelines the waits)
        uint4 g0[4];
#pragma unroll
        for (int j = 0; j < 4; ++j)
            g0[j] = egob_old[(unsigned)(cA0[j].x & COLM) * 8 + l8];
        // prefetch next cv quad (independent of the gathers)
        int2 cB0[4];
#pragma unroll
        for (int j = 0; j < 4; ++j) {
            int i0 = k0 + 4 + j; cB0[j] = sorted_cv[i0 < E0 ? i0 : CL0];
        }
        // consume; value masked to +0.0f past end (exact no-op, order kept)
#pragma unroll
        for (int j = 0; j < 4; ++j) {
            int vb0 = (k0 + j < E0) ? cA0[j].y : 0;
            EDGE8(acc0, vb0, g0[j]);
        }
        k0 += 4;
#pragma unroll
        for (int j = 0; j < 4; ++j) cA0[j] = cB0[j];
    }
    {
        float4 o0 = {acc0[0], acc0[1], acc0[2], acc0[3]};
        float4 o1 = {acc0[4], acc0[5], acc0[6], acc0[7]};
        *(float4*)&sideL[lr0 * SPAD + l8 * 8] = o0;
        *(float4*)&sideL[lr0 * SPAD + l8 * 8 + 4] = o1;
    }
    __syncthreads();

    // phase 2: wave pair shares a 16-row tile; each wave does 2 column-tiles.
    int m = lane & 15, quad = lane >> 4;
    int wr = wave >> 1, ch = wave & 1;
    int lr = wr * 16 + m;
    int base = base64 + wr * 16;
    int rowc = min(base64 + lr, n - 1);

    float4 s0 = *(const float4*)&sideL[lr * SPAD + quad * 8];
    float4 s1 = *(const float4*)&sideL[lr * SPAD + quad * 8 + 4];
    float4 s2 = *(const float4*)&sideL[lr * SPAD + 32 + quad * 8];
    float4 s3 = *(const float4*)&sideL[lr * SPAD + 32 + quad * 8 + 4];
    // R21: e from egob (bf16) — same values egob already carries; halves the
    // phase-2 ego stream (fabric-bound => direct time win)
    const uint4* brow = egob_old + (size_t)rowc * 8;
    uint4 eb0 = brow[quad];        // cols [quad*8, quad*8+8)
    uint4 eb1 = brow[4 + quad];    // cols [32+quad*8, 32+quad*8+8)

    bf16x8 aS_lo = pack8(s0.x, s0.y, s0.z, s0.w, s1.x, s1.y, s1.z, s1.w);
    bf16x8 aS_hi = pack8(s2.x, s2.y, s2.z, s2.w, s3.x, s3.y, s3.z, s3.w);
    bf16x8 aP_lo = pack8(BF_LO(eb0.x) * s0.x, BF_HI(eb0.x) * s0.y,
                         BF_LO(eb0.y) * s0.z, BF_HI(eb0.y) * s0.w,
                         BF_LO(eb0.z) * s1.x, BF_HI(eb0.z) * s1.y,
                         BF_LO(eb0.w) * s1.z, BF_HI(eb0.w) * s1.w);
    bf16x8 aP_hi = pack8(BF_LO(eb1.x) * s2.x, BF_HI(eb1.x) * s2.y,
                         BF_LO(eb1.y) * s2.z, BF_HI(eb1.y) * s2.w,
                         BF_LO(eb1.z) * s3.x, BF_HI(eb1.z) * s3.y,
                         BF_LO(eb1.w) * s3.z, BF_HI(eb1.w) * s3.w);

#pragma unroll
    for (int cti = 0; cti < 2; ++cti) {
        int ct = ch * 2 + cti;
        int col = ct * 16 + m;
        bf16x8 bg_lo = *(const bf16x8*)&sWg[col * WT_STRIDE + quad * 8];
        bf16x8 bg_hi = *(const bf16x8*)&sWg[col * WT_STRIDE + 32 + quad * 8];
        bf16x8 bb_lo = *(const bf16x8*)&sWb[col * WT_STRIDE + quad * 8];
        bf16x8 bb_hi = *(const bf16x8*)&sWb[col * WT_STRIDE + 32 + quad * 8];
        f32x4 accG = (f32x4){0.f, 0.f, 0.f, 0.f};
        f32x4 accB = (f32x4){0.f, 0.f, 0.f, 0.f};
        accG = __builtin_amdgcn_mfma_f32_16x16x32_bf16(aS_lo, bg_lo, accG, 0, 0, 0);
        accG = __builtin_amdgcn_mfma_f32_16x16x32_bf16(aS_hi, bg_hi, accG, 0, 0, 0);
        accB = __builtin_amdgcn_mfma_f32_16x16x32_bf16(aP_lo, bb_lo, accB, 0, 0, 0);
        accB = __builtin_amdgcn_mfma_f32_16x16x32_bf16(aP_hi, bb_hi, accB, 0, 0, 0);
        float bg = bgc[col], bb = bbi[col];
#pragma unroll
        for (int r = 0; r < 4; ++r) {
            int node = base + quad * 4 + r;
            if (node < n) {
                float o = leaky(accG[r] + bg) + leaky(accB[r] + bb);
                ego_new[(size_t)node * DD + col] = o;
                egob_new[(size_t)node * DD + col] = f2bf(o);
            }
        }
    }
}

// final-layer gather (layer L) stays standalone
__global__ void gather_kernel(const float* __restrict__ ego, const int* __restrict__ u,
                              const int* __restrict__ ii, const int* __restrict__ jj,
                              float* __restrict__ out, int layer, int B, int n_users,
                              int normalize, int ostride) {
    int wid = (blockIdx.x * blockDim.x + threadIdx.x) >> 6;
    int lane = threadIdx.x & 63;
    if (wid >= 3 * B) return;
    int arr = wid / B;
    int b = wid - arr * B;
    int node = (arr == 0) ? u[b] : ((arr == 1) ? n_users + ii[b] : n_users + jj[b]);
    float v = ego[(size_t)node * DD + lane];
    if (normalize) {
        float ss = v * v;
#pragma unroll
        for (int m = 32; m; m >>= 1) ss += __shfl_xor(ss, m, 64);
        v /= fmaxf(sqrtf(ss), 1e-12f);
    }
    out[(size_t)wid * ostride + layer * DD + lane] = v;
}

extern "C" void kernel_launch(void* const* d_in, const int* in_sizes, int n_in,
                              void* d_out, int out_size, void* d_ws, size_t ws_size,
                              hipStream_t stream) {
    const float* user_emb = (const float*)d_in[0];
    const float* item_emb = (const float*)d_in[1];
    const float* W_gc = (const float*)d_in[2];
    const float* b_gc = (const float*)d_in[3];
    const float* W_bi = (const float*)d_in[4];
    const float* b_bi = (const float*)d_in[5];
    const float* adj_vals = (const float*)d_in[6];
    const int* adj_rows = (const int*)d_in[7];
    const int* adj_cols = (const int*)d_in[8];
    const int* u = (const int*)d_in[9];
    const int* ii = (const int*)d_in[10];
    const int* jj = (const int*)d_in[11];
    float* out = (float*)d_out;

    const int D = DD;
    int n_users = in_sizes[0] / D;
    int n_items = in_sizes[1] / D;
    int n = n_users + n_items;
    int nnz = in_sizes[6];
    int B = in_sizes[9];
    int L = in_sizes[2] / (D * D);
    int ostride = (L + 1) * D;

    int nbuckets = (n + RB - 1) / RB;      // 586
    int flat = nbuckets * NBLKA;

    char* ws = (char*)d_ws;
    auto alloc = [&](size_t bytes) {
        char* p = ws;
        ws += (bytes + 255) & ~(size_t)255;
        return p;
    };
    float* ego_a = (float*)alloc((size_t)n * D * 4);
    float* ego_b = (float*)alloc((size_t)n * D * 4);
    ushort* egob_a = (ushort*)alloc((size_t)n * D * 2);
    ushort* egob_b = (ushort*)alloc((size_t)n * D * 2);
    int* counts_t = (int*)alloc((size_t)flat * 4);
    int* offsets = (int*)alloc((size_t)(flat + 1) * 4);
    int* blocksums = (int*)alloc(4096);
    int2* csr_cv = (int2*)alloc((size_t)nnz * 8);
    int2* sorted_cv = (int2*)alloc((size_t)nnz * 8);
    int* rowoff = (int*)alloc((size_t)(nbuckets * RB + 1) * 4);
    ushort* wt_g = (ushort*)alloc((size_t)L * D * D * 2);
    ushort* wt_b = (ushort*)alloc((size_t)L * D * D * 2);

    // 1. concat (fp32 + bf16 mirror) + one-time W transpose, merged
    int total4 = n * D / 4, nu4 = n_users * D / 4;
    int cblocks = (total4 + 255) / 256;
    concat_wtrans_kernel<<<cblocks + 2 * L, 256, 0, stream>>>(
        (const float4*)user_emb, (const float4*)item_emb, (float4*)ego_a, (ushort4*)egob_a,
        nu4, total4, cblocks, W_gc, W_bi, wt_g, wt_b, L);

    // 2. bucketed CSR build + ONE row-sort (flat contention-free offsets)
    bhist_kernel<<<NBLKA, 256, 0, stream>>>(adj_rows, counts_t, nnz, nbuckets);
    int nblk1 = (flat + 1023) / 1024;
    scan1_kernel<<<nblk1, 1024, 0, stream>>>(counts_t, offsets, blocksums, flat, nbuckets);
    scan2_kernel<<<1, 1024, 0, stream>>>(blocksums, nblk1);
    scan3_kernel<<<nblk1, 1024, 0, stream>>>(offsets, blocksums, flat);
    bscatter_kernel<<<NBLKA, 256, 0, stream>>>(adj_rows, adj_cols, adj_vals, offsets, csr_cv,
                                               nnz, nbuckets);
    sort_kernel<<<nbuckets, 256, 0, stream>>>(offsets, csr_cv, sorted_cv, rowoff, nnz, nbuckets);

    // 3. layers (ping-pong ego buffers); trailing blocks gather the INPUT
    //    (= previous layer's output; layer 0 input is raw ego, no norm)
    float* eo = ego_a; ushort* ebo = egob_a;
    float* en = ego_b; ushort* ebn = egob_b;
    int fblocks = (n + 63) / 64;
    int grows = 3 * B;
    int gblocks = (grows + 7) / 8;         // 8 waves per 512-thread block
    for (int l = 0; l < L; ++l) {
        fused_layer_kernel<<<fblocks + gblocks, 512, 0, stream>>>(
            (const uint4*)ebo, eo, en, ebn, rowoff, sorted_cv,
            wt_g + (size_t)l * D * D, b_gc + (size_t)l * D,
            wt_b + (size_t)l * D * D, b_bi + (size_t)l * D, n,
            fblocks, u, ii, jj, out, B, n_users, l, (l > 0) ? 1 : 0, ostride);
        float* tf = eo; eo = en; en = tf;
        ushort* tb = ebo; ebo = ebn; ebn = tb;
    }

    // 4. final-layer gather (normalized)
    gather_kernel<<<(grows + 3) / 4, 256, 0, stream>>>(eo, u, ii, jj, out, L, B, n_users, 1,
                                                       ostride);
}

// Round 13
// 415.991 us; speedup vs baseline: 1.0218x; 1.0218x over previous
//
#include <hip/hip_runtime.h>

#define DD 64
#define RB 256         // rows per bucket
#define RB_SHIFT 8
#define CAP 4608       // LDS-sorted edge capacity per bucket (avg 4096, +8 sigma)
#define NBLKA 512      // blocks in the two bucketing passes (pow2; must match)
#define NBLKA_SHIFT 9
#define BMAX 1024      // max buckets (n <= BMAX*RB, col fits 18 bits)
#define COLM 0x3FFFF
#define WT_STRIDE 80   // padded k-stride of transposed bf16 W in LDS (16B-aligned rows)
#define EMAX 4704      // R22: reverted to R20 value (R21's 2368 halving cost ~13us:
                       // doubled per-sub-chunk scan/hist overhead, no occupancy win)
#define SPAD 68        // padded fp32 stride of the LDS side tile (2-way max on frag reads)

typedef __attribute__((ext_vector_type(8))) short bf16x8;
typedef __attribute__((ext_vector_type(4))) float f32x4;

static __device__ __forceinline__ float leaky(float x) {
    return x > 0.f ? x : 0.2f * x;
}

// fp32 -> bf16 bits, round-to-nearest-even
static __device__ __forceinline__ unsigned short f2bf(float f) {
    unsigned u = __float_as_uint(f);
    unsigned r = 0x7FFFu + ((u >> 16) & 1u);
    return (unsigned short)((u + r) >> 16);
}
#define BF_LO(w) __int_as_float((int)((w) << 16))
#define BF_HI(w) __int_as_float((int)((w) & 0xFFFF0000u))

static __device__ __forceinline__ bf16x8 pack8(float a, float b, float c, float d,
                                               float e, float f, float g, float h) {
    bf16x8 r;
    r[0] = (short)f2bf(a); r[1] = (short)f2bf(b); r[2] = (short)f2bf(c); r[3] = (short)f2bf(d);
    r[4] = (short)f2bf(e); r[5] = (short)f2bf(f); r[6] = (short)f2bf(g); r[7] = (short)f2bf(h);
    return r;
}

// R19: concat + one-time W transpose merged (blockIdx branch).
// wtrans branch: W (fp32 [k][c]) -> Wt (bf16 [c][k]) via padded LDS tile —
// both global sides coalesced (R15 post-mortem).
__global__ void concat_wtrans_kernel(const float4* __restrict__ ue,
                                     const float4* __restrict__ ie,
                                     float4* __restrict__ ego, ushort4* __restrict__ egob,
                                     int n_user4, int total4, int cblocks,
                                     const float* __restrict__ Wg, const float* __restrict__ Wb,
                                     ushort* __restrict__ wtg, ushort* __restrict__ wtb, int L) {
    __shared__ ushort t[64][65];
    int tid = threadIdx.x;
    if ((int)blockIdx.x >= cblocks) {
        int which = blockIdx.x - cblocks;  // 0..2L-1
        const float* src = (which < L) ? Wg + (size_t)which * 4096
                                       : Wb + (size_t)(which - L) * 4096;
        ushort* dst = (which < L) ? wtg + (size_t)which * 4096
                                  : wtb + (size_t)(which - L) * 4096;
        for (int i = tid; i < 4096; i += 256) {
            int k = i >> 6, c = i & 63;
            t[k][c] = f2bf(src[i]);      // coalesced read; 2B-stride LDS write
        }
        __syncthreads();
        for (int i = tid; i < 4096; i += 256) {
            int c = i >> 6, k = i & 63;
            dst[i] = t[k][c];            // coalesced write; ~2-way LDS read (65-pad)
        }
        return;
    }
    int idx = blockIdx.x * 256 + tid;
    if (idx >= total4) return;
    float4 v = (idx < n_user4) ? ue[idx] : ie[idx - n_user4];
    ego[idx] = v;
    ushort4 b;
    b.x = f2bf(v.x); b.y = f2bf(v.y); b.z = f2bf(v.z); b.w = f2bf(v.w);
    egob[idx] = b;
}

// pass A: per-(bucket, block) histogram via LDS — no global atomics.
// Flat per-(bucket,block) offsets (R19 post-mortem: global atomic cursors
// serialized bscatter — 512 blocks blocking on same-address atomic returns).
__global__ void bhist_kernel(const int* __restrict__ rows, int* __restrict__ counts_t, int nnz,
                             int nbuckets) {
    __shared__ int h[BMAX];
    int tid = threadIdx.x, blk = blockIdx.x;
    for (int i = tid; i < nbuckets; i += 256) h[i] = 0;
    __syncthreads();
    int chunk = (nnz + NBLKA - 1) / NBLKA;
    int lo = blk * chunk, hi = min(nnz, lo + chunk);
    for (int e = lo + tid; e < hi; e += 256) atomicAdd(&h[rows[e] >> RB_SHIFT], 1);
    __syncthreads();
    for (int i = tid; i < nbuckets; i += 256) counts_t[blk * nbuckets + i] = h[i];
}

// scan over flat order f = bucket*NBLKA + blk, reading transposed counts.
__global__ void scan1_kernel(const int* __restrict__ counts_t, int* __restrict__ offsets,
                             int* __restrict__ blocksums, int flat, int nbuckets) {
    __shared__ int tmp[1024];
    int t = threadIdx.x;
    int g = blockIdx.x * 1024 + t;
    int x = 0;
    if (g < flat) {
        int i = g >> NBLKA_SHIFT, blk = g & (NBLKA - 1);
        x = counts_t[blk * nbuckets + i];
    }
    tmp[t] = x;
    __syncthreads();
    for (int off = 1; off < 1024; off <<= 1) {
        int y = (t >= off) ? tmp[t - off] : 0;
        __syncthreads();
        tmp[t] += y;
        __syncthreads();
    }
    if (g < flat) offsets[g + 1] = tmp[t];
    if (t == 1023) blocksums[blockIdx.x] = tmp[t];
    if (g == 0) offsets[0] = 0;
}

__global__ void scan2_kernel(int* blocksums, int nb) {
    __shared__ int tmp[1024];
    int t = threadIdx.x;
    int v = (t < nb) ? blocksums[t] : 0;
    tmp[t] = v;
    __syncthreads();
    for (int off = 1; off < 1024; off <<= 1) {
        int y = (t >= off) ? tmp[t - off] : 0;
        __syncthreads();
        tmp[t] += y;
        __syncthreads();
    }
    if (t < nb) blocksums[t] = tmp[t] - v;  // exclusive base per block
}

__global__ void scan3_kernel(int* __restrict__ offsets, const int* __restrict__ blocksums,
                             int n) {
    int g = blockIdx.x * 1024 + threadIdx.x;
    if (g < n) offsets[g + 1] += blocksums[blockIdx.x];
}

// pass B: LDS bucket-sort the block's chunk, then write back with consecutive
// lanes -> consecutive global addresses (coalesced path is load-bearing —
// R14: direct random 8B scatter = 8x write amplification). Write bases come
// from the precomputed contention-free offset table.
__global__ void __launch_bounds__(256) bscatter_kernel(
    const int* __restrict__ rows, const int* __restrict__ cols,
    const float* __restrict__ vals, const int* __restrict__ offsets,
    int2* __restrict__ csr_cv, int nnz, int nbuckets) {
    __shared__ int hist[BMAX];
    __shared__ int lbase[BMAX];
    __shared__ int cur[BMAX];
    __shared__ int gcur[BMAX];
    __shared__ int tsum[256];
    __shared__ int2 buf[EMAX];
    __shared__ int dst[EMAX];
    int tid = threadIdx.x, blk = blockIdx.x;
    int chunk = (nnz + NBLKA - 1) / NBLKA;
    int lo = blk * chunk, hi = min(nnz, lo + chunk);
    for (int i = tid; i < BMAX; i += 256)
        gcur[i] = (i < nbuckets) ? offsets[i * NBLKA + blk] : 0;
    for (int sub = lo; sub < hi; sub += EMAX) {
        int scount = min(EMAX, hi - sub);
        for (int i = tid; i < BMAX; i += 256) hist[i] = 0;
        __syncthreads();
        for (int e = sub + tid; e < sub + scount; e += 256)
            atomicAdd(&hist[rows[e] >> RB_SHIFT], 1);
        __syncthreads();
        int loc[4];
        int s = 0;
        int bi = tid * 4;
#pragma unroll
        for (int j = 0; j < 4; ++j) { loc[j] = s; s += hist[bi + j]; }
        tsum[tid] = s;
        __syncthreads();
        for (int off = 1; off < 256; off <<= 1) {
            int v = (tid >= off) ? tsum[tid - off] : 0;
            __syncthreads();
            tsum[tid] += v;
            __syncthreads();
        }
        int excl = tid ? tsum[tid - 1] : 0;
#pragma unroll
        for (int j = 0; j < 4; ++j) {
            lbase[bi + j] = excl + loc[j];
            cur[bi + j] = excl + loc[j];
        }
        __syncthreads();
        for (int e = sub + tid; e < sub + scount; e += 256) {
            int r = rows[e];
            int b = r >> RB_SHIFT;
            int p = atomicAdd(&cur[b], 1);
            int2 cv;
            cv.x = ((r & (RB - 1)) << 18) | cols[e];  // row_low(8b) | col(18b)
            cv.y = __float_as_int(vals[e]);
            buf[p] = cv;
            dst[p] = gcur[b] + (p - lbase[b]);
        }
        __syncthreads();
        for (int k = tid; k < scount; k += 256) csr_cv[dst[k]] = buf[k];
        __syncthreads();
        for (int i = tid; i < BMAX; i += 256) gcur[i] += hist[i];
        __syncthreads();
    }
}

// ONE-TIME sort: per bucket, counting-sort edges by row; LDS fast path, direct
// global scatter fallback for oversized buckets.
__global__ void __launch_bounds__(256) sort_kernel(
    const int* __restrict__ offsets, const int2* __restrict__ csr_cv,
    int2* __restrict__ sorted_cv, int* __restrict__ rowoff_g, int nnz, int nbuckets) {
    __shared__ int2 sorted[CAP];
    __shared__ int hist[RB];
    __shared__ int rowoff[RB + 1];
    __shared__ int cur[RB];
    int tid = threadIdx.x;
    int b = blockIdx.x;
    int s = offsets[b * NBLKA];
    int e = offsets[(b + 1) * NBLKA];
    int m = e - s;

    hist[tid] = 0;
    __syncthreads();
    for (int k = s + tid; k < e; k += 256)
        atomicAdd(&hist[((unsigned)csr_cv[k].x) >> 18], 1);
    __syncthreads();
    for (int off = 1; off < RB; off <<= 1) {
        int v = (tid >= off) ? hist[tid - off] : 0;
        __syncthreads();
        hist[tid] += v;
        __syncthreads();
    }
    rowoff[tid + 1] = hist[tid];
    if (tid == 0) rowoff[0] = 0;
    __syncthreads();
    cur[tid] = rowoff[tid];
    __syncthreads();
    if (m <= CAP) {
        for (int k = s + tid; k < e; k += 256) {
            int2 cv = csr_cv[k];
            int p = atomicAdd(&cur[((unsigned)cv.x) >> 18], 1);
            sorted[p] = cv;
        }
        __syncthreads();
        for (int k = tid; k < m; k += 256) sorted_cv[s + k] = sorted[k];
    } else {
        // rare fallback: scatter straight to global (uncoalesced, correct)
        for (int k = s + tid; k < e; k += 256) {
            int2 cv = csr_cv[k];
            int p = atomicAdd(&cur[((unsigned)cv.x) >> 18], 1);
            sorted_cv[s + p] = cv;
        }
    }
    rowoff_g[b * RB + tid] = s + rowoff[tid];
    if (b == 0 && tid == 0) rowoff_g[nbuckets * RB] = nnz;
}

// per-edge accumulate: acc[0..7] += v * unpack(g)
#define EDGE8(acc, cvy, g)                                                     \
    do {                                                                       \
        float v_ = __int_as_float(cvy);                                        \
        acc[0] += v_ * BF_LO((g).x); acc[1] += v_ * BF_HI((g).x);              \
        acc[2] += v_ * BF_LO((g).y); acc[3] += v_ * BF_HI((g).y);              \
        acc[4] += v_ * BF_LO((g).z); acc[5] += v_ * BF_HI((g).z);              \
        acc[6] += v_ * BF_LO((g).w); acc[7] += v_ * BF_HI((g).w);              \
    } while (0)

// FUSED layer: spmm (side into LDS) + MFMA transform, per 64-row block,
// 512 threads / 8 waves (32 waves/CU; phase 1 at the random-gather fabric
// wall — rate pinned ~3.45 TB/s, so traffic cuts convert to time).
// R21 (kept): phase-2 bi-interaction input e read from egob (bf16) instead
// of ego (fp32) — product is bf16-rounded by pack8 anyway. Trailing blocks
// perform the PREVIOUS layer's output gather (R19).
__global__ void __launch_bounds__(512, 8) fused_layer_kernel(
    const uint4* __restrict__ egob_old, const float* __restrict__ ego_old,
    float* __restrict__ ego_new, ushort* __restrict__ egob_new,
    const int* __restrict__ rowoff, const int2* __restrict__ sorted_cv,
    const ushort* __restrict__ Wtg, const float* __restrict__ bgc,
    const ushort* __restrict__ Wtb, const float* __restrict__ bbi, int n,
    int fblocks, const int* __restrict__ u, const int* __restrict__ ii,
    const int* __restrict__ jj, float* __restrict__ out, int B, int n_users,
    int glayer, int gnorm, int ostride) {
    __shared__ __align__(16) float sideL[64 * SPAD];
    __shared__ __align__(16) ushort sWg[DD * WT_STRIDE];
    __shared__ __align__(16) ushort sWb[DD * WT_STRIDE];
    int tid = threadIdx.x;
    int wave = tid >> 6, lane = tid & 63;

    if ((int)blockIdx.x >= fblocks) {
        // gather branch: one wave per (arr, b) id; reads ego_old (prev output)
        int wid = (blockIdx.x - fblocks) * 8 + wave;
        if (wid < 3 * B) {
            int arr = wid / B;
            int b = wid - arr * B;
            int node = (arr == 0) ? u[b] : ((arr == 1) ? n_users + ii[b] : n_users + jj[b]);
            float v = ego_old[(size_t)node * DD + lane];
            if (gnorm) {
                float ss = v * v;
#pragma unroll
                for (int m = 32; m; m >>= 1) ss += __shfl_xor(ss, m, 64);
                v /= fmaxf(sqrtf(ss), 1e-12f);
            }
            out[(size_t)wid * ostride + glayer * DD + lane] = v;
        }
        return;
    }

    // staging: Wt is [c][k] bf16; coalesced global read, conflict-free LDS write
    for (int idx = tid; idx < DD * DD / 4; idx += 512) {
        int c = idx >> 4, k4 = idx & 15;
        *(ushort4*)&sWg[c * WT_STRIDE + k4 * 4] = ((const ushort4*)Wtg)[idx];
        *(ushort4*)&sWb[c * WT_STRIDE + k4 * 4] = ((const ushort4*)Wtb)[idx];
    }
    int base64 = blockIdx.x * 64;
    int sub = lane >> 3, l8 = lane & 7;

    // phase 1: single-stream spmm, 8 waves x 8 rows
    int lr0 = wave * 8 + sub;
    int row0 = base64 + lr0;
    float acc0[8] = {0.f, 0.f, 0.f, 0.f, 0.f, 0.f, 0.f, 0.f};
    int k0 = 0, E0 = 0;
    if (row0 < n) { k0 = rowoff[row0]; E0 = rowoff[row0 + 1]; }
    int CL0 = (E0 > 0) ? E0 - 1 : 0;   // clamped (valid, cache-hot) edge index

    // wave-uniform trip count: max over the 8 lane-groups (lane bits 3..5)
    int myit = (E0 - k0 + 3) >> 2;
    myit = max(myit, __shfl_xor(myit, 8, 64));
    myit = max(myit, __shfl_xor(myit, 16, 64));
    myit = max(myit, __shfl_xor(myit, 32, 64));

    int2 cA0[4];
#pragma unroll
    for (int j = 0; j < 4; ++j) {
        int i0 = k0 + j; cA0[j] = sorted_cv[i0 < E0 ? i0 : CL0];
    }
    for (int it = 0; it < myit; ++it) {
        // issue the 4 gathers (straight-line: compiler pipelines the waits)
        uint4 g0[4];
#pragma unroll
        for (int j = 0; j < 4; ++j)
            g0[j] = egob_old[(unsigned)(cA0[j].x & COLM) * 8 + l8];
        // prefetch next cv quad (independent of the gathers)
        int2 cB0[4];
#pragma unroll
        for (int j = 0; j < 4; ++j) {
            int i0 = k0 + 4 + j; cB0[j] = sorted_cv[i0 < E0 ? i0 : CL0];
        }
        // consume; value masked to +0.0f past end (exact no-op, order kept)
#pragma unroll
        for (int j = 0; j < 4; ++j) {
            int vb0 = (k0 + j < E0) ? cA0[j].y : 0;
            EDGE8(acc0, vb0, g0[j]);
        }
        k0 += 4;
#pragma unroll
        for (int j = 0; j < 4; ++j) cA0[j] = cB0[j];
    }
    {
        float4 o0 = {acc0[0], acc0[1], acc0[2], acc0[3]};
        float4 o1 = {acc0[4], acc0[5], acc0[6], acc0[7]};
        *(float4*)&sideL[lr0 * SPAD + l8 * 8] = o0;
        *(float4*)&sideL[lr0 * SPAD + l8 * 8 + 4] = o1;
    }
    __syncthreads();

    // phase 2: wave pair shares a 16-row tile; each wave does 2 column-tiles.
    int m = lane & 15, quad = lane >> 4;
    int wr = wave >> 1, ch = wave & 1;
    int lr = wr * 16 + m;
    int base = base64 + wr * 16;
    int rowc = min(base64 + lr, n - 1);

    float4 s0 = *(const float4*)&sideL[lr * SPAD + quad * 8];
    float4 s1 = *(const float4*)&sideL[lr * SPAD + quad * 8 + 4];
    float4 s2 = *(const float4*)&sideL[lr * SPAD + 32 + quad * 8];
    float4 s3 = *(const float4*)&sideL[lr * SPAD + 32 + quad * 8 + 4];
    // R21: e from egob (bf16) — same values egob already carries; halves the
    // phase-2 ego stream (fabric-bound => direct time win)
    const uint4* brow = egob_old + (size_t)rowc * 8;
    uint4 eb0 = brow[quad];        // cols [quad*8, quad*8+8)
    uint4 eb1 = brow[4 + quad];    // cols [32+quad*8, 32+quad*8+8)

    bf16x8 aS_lo = pack8(s0.x, s0.y, s0.z, s0.w, s1.x, s1.y, s1.z, s1.w);
    bf16x8 aS_hi = pack8(s2.x, s2.y, s2.z, s2.w, s3.x, s3.y, s3.z, s3.w);
    bf16x8 aP_lo = pack8(BF_LO(eb0.x) * s0.x, BF_HI(eb0.x) * s0.y,
                         BF_LO(eb0.y) * s0.z, BF_HI(eb0.y) * s0.w,
                         BF_LO(eb0.z) * s1.x, BF_HI(eb0.z) * s1.y,
                         BF_LO(eb0.w) * s1.z, BF_HI(eb0.w) * s1.w);
    bf16x8 aP_hi = pack8(BF_LO(eb1.x) * s2.x, BF_HI(eb1.x) * s2.y,
                         BF_LO(eb1.y) * s2.z, BF_HI(eb1.y) * s2.w,
                         BF_LO(eb1.z) * s3.x, BF_HI(eb1.z) * s3.y,
                         BF_LO(eb1.w) * s3.z, BF_HI(eb1.w) * s3.w);

#pragma unroll
    for (int cti = 0; cti < 2; ++cti) {
        int ct = ch * 2 + cti;
        int col = ct * 16 + m;
        bf16x8 bg_lo = *(const bf16x8*)&sWg[col * WT_STRIDE + quad * 8];
        bf16x8 bg_hi = *(const bf16x8*)&sWg[col * WT_STRIDE + 32 + quad * 8];
        bf16x8 bb_lo = *(const bf16x8*)&sWb[col * WT_STRIDE + quad * 8];
        bf16x8 bb_hi = *(const bf16x8*)&sWb[col * WT_STRIDE + 32 + quad * 8];
        f32x4 accG = (f32x4){0.f, 0.f, 0.f, 0.f};
        f32x4 accB = (f32x4){0.f, 0.f, 0.f, 0.f};
        accG = __builtin_amdgcn_mfma_f32_16x16x32_bf16(aS_lo, bg_lo, accG, 0, 0, 0);
        accG = __builtin_amdgcn_mfma_f32_16x16x32_bf16(aS_hi, bg_hi, accG, 0, 0, 0);
        accB = __builtin_amdgcn_mfma_f32_16x16x32_bf16(aP_lo, bb_lo, accB, 0, 0, 0);
        accB = __builtin_amdgcn_mfma_f32_16x16x32_bf16(aP_hi, bb_hi, accB, 0, 0, 0);
        float bg = bgc[col], bb = bbi[col];
#pragma unroll
        for (int r = 0; r < 4; ++r) {
            int node = base + quad * 4 + r;
            if (node < n) {
                float o = leaky(accG[r] + bg) + leaky(accB[r] + bb);
                ego_new[(size_t)node * DD + col] = o;
                egob_new[(size_t)node * DD + col] = f2bf(o);
            }
        }
    }
}

// final-layer gather (layer L) stays standalone
__global__ void gather_kernel(const float* __restrict__ ego, const int* __restrict__ u,
                              const int* __restrict__ ii, const int* __restrict__ jj,
                              float* __restrict__ out, int layer, int B, int n_users,
                              int normalize, int ostride) {
    int wid = (blockIdx.x * blockDim.x + threadIdx.x) >> 6;
    int lane = threadIdx.x & 63;
    if (wid >= 3 * B) return;
    int arr = wid / B;
    int b = wid - arr * B;
    int node = (arr == 0) ? u[b] : ((arr == 1) ? n_users + ii[b] : n_users + jj[b]);
    float v = ego[(size_t)node * DD + lane];
    if (normalize) {
        float ss = v * v;
#pragma unroll
        for (int m = 32; m; m >>= 1) ss += __shfl_xor(ss, m, 64);
        v /= fmaxf(sqrtf(ss), 1e-12f);
    }
    out[(size_t)wid * ostride + layer * DD + lane] = v;
}

extern "C" void kernel_launch(void* const* d_in, const int* in_sizes, int n_in,
                              void* d_out, int out_size, void* d_ws, size_t ws_size,
                              hipStream_t stream) {
    const float* user_emb = (const float*)d_in[0];
    const float* item_emb = (const float*)d_in[1];
    const float* W_gc = (const float*)d_in[2];
    const float* b_gc = (const float*)d_in[3];
    const float* W_bi = (const float*)d_in[4];
    const float* b_bi = (const float*)d_in[5];
    const float* adj_vals = (const float*)d_in[6];
    const int* adj_rows = (const int*)d_in[7];
    const int* adj_cols = (const int*)d_in[8];
    const int* u = (const int*)d_in[9];
    const int* ii = (const int*)d_in[10];
    const int* jj = (const int*)d_in[11];
    float* out = (float*)d_out;

    const int D = DD;
    int n_users = in_sizes[0] / D;
    int n_items = in_sizes[1] / D;
    int n = n_users + n_items;
    int nnz = in_sizes[6];
    int B = in_sizes[9];
    int L = in_sizes[2] / (D * D);
    int ostride = (L + 1) * D;

    int nbuckets = (n + RB - 1) / RB;      // 586
    int flat = nbuckets * NBLKA;

    char* ws = (char*)d_ws;
    auto alloc = [&](size_t bytes) {
        char* p = ws;
        ws += (bytes + 255) & ~(size_t)255;
        return p;
    };
    float* ego_a = (float*)alloc((size_t)n * D * 4);
    float* ego_b = (float*)alloc((size_t)n * D * 4);
    ushort* egob_a = (ushort*)alloc((size_t)n * D * 2);
    ushort* egob_b = (ushort*)alloc((size_t)n * D * 2);
    int* counts_t = (int*)alloc((size_t)flat * 4);
    int* offsets = (int*)alloc((size_t)(flat + 1) * 4);
    int* blocksums = (int*)alloc(4096);
    int2* csr_cv = (int2*)alloc((size_t)nnz * 8);
    int2* sorted_cv = (int2*)alloc((size_t)nnz * 8);
    int* rowoff = (int*)alloc((size_t)(nbuckets * RB + 1) * 4);
    ushort* wt_g = (ushort*)alloc((size_t)L * D * D * 2);
    ushort* wt_b = (ushort*)alloc((size_t)L * D * D * 2);

    // 1. concat (fp32 + bf16 mirror) + one-time W transpose, merged
    int total4 = n * D / 4, nu4 = n_users * D / 4;
    int cblocks = (total4 + 255) / 256;
    concat_wtrans_kernel<<<cblocks + 2 * L, 256, 0, stream>>>(
        (const float4*)user_emb, (const float4*)item_emb, (float4*)ego_a, (ushort4*)egob_a,
        nu4, total4, cblocks, W_gc, W_bi, wt_g, wt_b, L);

    // 2. bucketed CSR build + ONE row-sort (flat contention-free offsets)
    bhist_kernel<<<NBLKA, 256, 0, stream>>>(adj_rows, counts_t, nnz, nbuckets);
    int nblk1 = (flat + 1023) / 1024;
    scan1_kernel<<<nblk1, 1024, 0, stream>>>(counts_t, offsets, blocksums, flat, nbuckets);
    scan2_kernel<<<1, 1024, 0, stream>>>(blocksums, nblk1);
    scan3_kernel<<<nblk1, 1024, 0, stream>>>(offsets, blocksums, flat);
    bscatter_kernel<<<NBLKA, 256, 0, stream>>>(adj_rows, adj_cols, adj_vals, offsets, csr_cv,
                                               nnz, nbuckets);
    sort_kernel<<<nbuckets, 256, 0, stream>>>(offsets, csr_cv, sorted_cv, rowoff, nnz, nbuckets);

    // 3. layers (ping-pong ego buffers); trailing blocks gather the INPUT
    //    (= previous layer's output; layer 0 input is raw ego, no norm)
    float* eo = ego_a; ushort* ebo = egob_a;
    float* en = ego_b; ushort* ebn = egob_b;
    int fblocks = (n + 63) / 64;
    int grows = 3 * B;
    int gblocks = (grows + 7) / 8;         // 8 waves per 512-thread block
    for (int l = 0; l < L; ++l) {
        fused_layer_kernel<<<fblocks + gblocks, 512, 0, stream>>>(
            (const uint4*)ebo, eo, en, ebn, rowoff, sorted_cv,
            wt_g + (size_t)l * D * D, b_gc + (size_t)l * D,
            wt_b + (size_t)l * D * D, b_bi + (size_t)l * D, n,
            fblocks, u, ii, jj, out, B, n_users, l, (l > 0) ? 1 : 0, ostride);
        float* tf = eo; eo = en; en = tf;
        ushort* tb = ebo; ebo = ebn; ebn = tb;
    }

    // 4. final-layer gather (normalized)
    gather_kernel<<<(grows + 3) / 4, 256, 0, stream>>>(eo, u, ii, jj, out, L, B, n_users, 1,
                                                       ostride);
}